// Round 11
// baseline (191.476 us; speedup 1.0000x reference)
//
#include <hip/hip_runtime.h>
#include <hip/hip_bf16.h>

#define BB 4
#define CC 256
#define NN 4096
#define NSPLIT 4
#define KSPLIT (NN / NSPLIT)
#define NPAIR (KSPLIT / 64)

typedef __attribute__((ext_vector_type(8))) short short8;
typedef __attribute__((ext_vector_type(4))) float floatx4;
typedef __attribute__((ext_vector_type(4))) unsigned short ushortx4;

__device__ __forceinline__ float bf2f(unsigned short u) {
  union { unsigned int i; float f; } cv; cv.i = ((unsigned int)u) << 16; return cv.f;
}
__device__ __forceinline__ unsigned short f2bf(float f) {
  union { __hip_bfloat16 h; unsigned short u; } cv; cv.h = __float2bfloat16(f); return cv.u;
}
// pack two f32 -> two bf16 in one u32 (src0 -> low16). No builtin on gfx950.
__device__ __forceinline__ unsigned int cvtpk_bf16(float lo, float hi) {
  unsigned int r;
  asm("v_cvt_pk_bf16_f32 %0, %1, %2" : "=v"(r) : "v"(lo), "v"(hi));
  return r;
}

#define MFMA(a, b, c) __builtin_amdgcn_mfma_f32_16x16x32_bf16((a), (b), (c), 0, 0, 0)

// async global->LDS DMA, 16B/lane, LDS dest = wave-uniform base + lane*16
__device__ __forceinline__ void dma16(const unsigned short* g, unsigned short* l) {
  __builtin_amdgcn_global_load_lds(
      (const __attribute__((address_space(1))) unsigned int*)g,
      (__attribute__((address_space(3))) unsigned int*)l, 16, 0, 0);
}
#define S_BARRIER __builtin_amdgcn_s_barrier()
#define MEMFENCE __asm__ volatile("" ::: "memory")

// ---------------------------------------------------------------------------
// Phase 0: fp32 weights -> bf16 (y<3). Wq pre-scaled by C^-0.5 * log2(e).
// y==3: build the 256x64 positional-encoding table PEt[c][pos].
// PEt[c][p] = (c&64) ? cos(p * f) : sin(p * f),  f = 10000^-((c&63)/64).
// ---------------------------------------------------------------------------
__global__ __launch_bounds__(256) void wcvt(const float* __restrict__ w0,
                                            const float* __restrict__ w1,
                                            const float* __restrict__ w2,
                                            unsigned short* __restrict__ o0,
                                            unsigned short* __restrict__ o1,
                                            unsigned short* __restrict__ o2,
                                            float* __restrict__ PEt) {
  if (blockIdx.y == 3) {  // PE table: 64 blocks x 256 thr = 16384 entries
    int idx = blockIdx.x * 256 + threadIdx.x;
    int c = idx >> 6, p = idx & 63, j = c & 63;
    float freq = exp2f(-0.2076205059304601f * (float)j);  // 10000^(-j/64)
    float arg = (float)p * freq;
    PEt[idx] = (c & 64) ? cosf(arg) : sinf(arg);
    return;
  }
  const float* w = (blockIdx.y == 0) ? w0 : (blockIdx.y == 1) ? w1 : w2;
  unsigned short* o = (blockIdx.y == 0) ? o0 : (blockIdx.y == 1) ? o1 : o2;
  float s = (blockIdx.y == 0) ? 0.0901684400555590f : 1.0f;  // 0.0625*log2(e)
  int i = (blockIdx.x * 256 + threadIdx.x) * 4;
  floatx4 v = *(const floatx4*)&w[i];
  ushortx4 p;
#pragma unroll
  for (int r = 0; r < 4; r++) p[r] = f2bf(v[r] * s);
  *(ushortx4*)&o[i] = p;
}

// ---------------------------------------------------------------------------
// Phase 1: Xbf[b][n][c] = bf16( x[b][c][n] + PEt[c][w or h] ), LDS transpose.
// Table lookup: c<128 rows read 32 contiguous floats (coalesced); c>=128
// rows broadcast one float. 64 KB table is L2-resident.
// ---------------------------------------------------------------------------
__global__ __launch_bounds__(256) void prep_x(const float* __restrict__ x,
                                              const float* __restrict__ PEt,
                                              unsigned short* __restrict__ Xbf) {
  __shared__ float tile[32][33];
  int b = blockIdx.z;
  int n0 = blockIdx.x * 32, c0 = blockIdx.y * 32;
  int tx = threadIdx.x, ty = threadIdx.y;
#pragma unroll
  for (int i = 0; i < 4; i++) {
    int c = c0 + ty + i * 8;
    int n = n0 + tx;
    float v = x[((long)(b * CC + c)) * NN + n];
    int hh = n >> 6, ww = n & 63;
    v += PEt[(c << 6) | ((c < 128) ? ww : hh)];
    tile[ty + i * 8][tx] = v;
  }
  __syncthreads();
#pragma unroll
  for (int i = 0; i < 4; i++) {
    int n = n0 + ty + i * 8;
    int c = c0 + tx;
    Xbf[((long)(b * NN + n)) * CC + c] = f2bf(tile[tx][ty + i * 8]);
  }
}

// ---------------------------------------------------------------------------
// Phase 2 (m97-class): fused 128x128-tile GEMM, C = A * Bt^T, K=256, bf16.
// Flat grid 768: F<512 -> QK = Xbf * Wqk^T (4096x512/batch);
//                F>=512 -> Vt = Wv * Xbf^T (256x4096/batch).
// ---------------------------------------------------------------------------
__global__ __launch_bounds__(256, 2) void gemm_fused(const unsigned short* __restrict__ Xbf,
                                                     const unsigned short* __restrict__ Wqk,
                                                     const unsigned short* __restrict__ Wv,
                                                     unsigned short* __restrict__ QK,
                                                     unsigned short* __restrict__ Vt) {
  __shared__ alignas(16) unsigned short Af[2][8 * 512];  // 8 KB per buf
  __shared__ alignas(16) unsigned short Bf[2][8 * 512];
  const unsigned short *Ab, *Bb;
  unsigned short* Ob;
  long row0, col0;
  int ldo;
  int F = blockIdx.x;
  if (F < 512) {  // QK projection: A=Xbf(4096x256), Bt=Wqk(512x256), O=(B,N,512)
    int b = F >> 7, r = F & 127;
    row0 = (long)(r >> 2) * 128;  // 32 row tiles
    col0 = (long)(r & 3) * 128;   // 4 col tiles
    Ab = Xbf + (long)b * NN * CC;
    Bb = Wqk;
    Ob = QK + (long)b * NN * 512;
    ldo = 512;
  } else {  // Vt: A=Wv(256x256), Bt=Xbf(4096x256), O=(B,C,N)
    int F2 = F - 512;
    int b = F2 >> 6, r = F2 & 63;
    row0 = (long)(r >> 5) * 128;  // 2 row tiles
    col0 = (long)(r & 31) * 128;  // 32 col tiles
    Ab = Wv;
    Bb = Xbf + (long)b * NN * CC;
    Ob = Vt + (long)b * CC * NN;
    ldo = NN;
  }
  int t = threadIdx.x, wave = t >> 6, lane = t & 63, quad = lane >> 4, l15 = lane & 15;
  int wr = wave >> 1, wc = wave & 1;

  // stage k-chunk [k0,k0+32) into buffer `buf`: 16 fragment-groups, 4/wave
  auto stage = [&](int k0, int buf) {
#pragma unroll
    for (int i = 0; i < 2; i++) {
      int fg = wave * 2 + i;  // 0..7, wave-uniform
      dma16(&Ab[(row0 + fg * 16 + l15) * 256 + k0 + quad * 8], &Af[buf][fg * 512]);
      dma16(&Bb[(col0 + fg * 16 + l15) * 256 + k0 + quad * 8], &Bf[buf][fg * 512]);
    }
  };

  floatx4 acc[4][4] = {};
  stage(0, 0);
  MEMFENCE;
#pragma unroll
  for (int ki = 0; ki < 8; ki++) {
    int buf = ki & 1;
    S_BARRIER;  // all waves done reading buf (from step ki-2) -> overwrite ok
    MEMFENCE;
    if (ki + 1 < 8) {
      stage((ki + 1) * 32, buf ^ 1);
      MEMFENCE;
      __builtin_amdgcn_s_waitcnt(0xF74);  // vmcnt(4): my step-ki DMAs done
    } else {
      __builtin_amdgcn_s_waitcnt(0xF70);  // vmcnt(0)
    }
    S_BARRIER;  // step-ki fragments visible to all waves
    MEMFENCE;
    short8 af[4], bf[4];
#pragma unroll
    for (int i = 0; i < 4; i++) {
      af[i] = *(const short8*)&Af[buf][(wr * 4 + i) * 512 + lane * 8];
      bf[i] = *(const short8*)&Bf[buf][(wc * 4 + i) * 512 + lane * 8];
    }
#pragma unroll
    for (int i = 0; i < 4; i++)
#pragma unroll
      for (int j = 0; j < 4; j++) acc[i][j] = MFMA(af[i], bf[j], acc[i][j]);
  }

  // C/D layout (m89): col = l15, row = quad*4 + r (within each 16x16 block)
#pragma unroll
  for (int i = 0; i < 4; i++)
#pragma unroll
    for (int j = 0; j < 4; j++) {
      long col = col0 + (wc * 4 + j) * 16 + l15;
#pragma unroll
      for (int r = 0; r < 4; r++) {
        long row = row0 + (wr * 4 + i) * 16 + quad * 4 + r;
        Ob[row * (long)ldo + col] = f2bf(acc[i][j][r]);
      }
    }
}

// ---------------------------------------------------------------------------
// Phase 3: flash attention, no online max (|s*sc| <= ~35 log2-units, safe).
// 8-wave WG = 256 q-rows; grid 256 = 1 WG/CU. 4-slot LDS ring: pairs of
// 32-key tiles; barriers once per 64-key pair. VERIFIED round-1 schedule
// (B1 -> stage(p+1) -> vmcnt(8) -> B2 -> compute(p)) -- byte-identical.
// NOTE: the s_setprio brackets are LOAD-BEARING (round-10 lesson): they act
// as machine-scheduler fences keeping the ds_reads of Kl/Vl below the manual
// vmcnt waits. Removing them let hipcc hoist LDS reads above the waitcnt ->
// absmax 6.9e14. Do not remove or move them without disasm verification.
// SWAPPED QK^T (T12): S = MFMA(K,Q) puts q on l15, so the P transpose to the
// PV A-fragment is a quad-only lane permutation done fully in registers:
// exp2 -> v_cvt_pk_bf16_f32 -> ds_bpermute + cndmask. No P LDS buffer, no
// in-loop fences, no P bank conflicts.
// QK layout (B,N,512): [0:256)=Q (pre-scaled), [256:512)=K. Vt (B,C,N).
// ---------------------------------------------------------------------------
__global__ __launch_bounds__(512) void attn(const unsigned short* __restrict__ QKg,
                                            const unsigned short* __restrict__ Vtg,
                                            unsigned short* __restrict__ Opart,
                                            float* __restrict__ Lp) {
  __shared__ alignas(16) unsigned short Kl[4 * 8192];   // 4 slots x (32 keys x 256 d)
  __shared__ alignas(16) unsigned short Vl[4 * 8192];   // 4 slots x (256 d x 32 keys)
  int F = blockIdx.x;
  int c = F & 15, sp = c & 3, b = c >> 2;
  long q0 = (long)(F >> 4) * 256;
  int t = threadIdx.x, wave = t >> 6, lane = t & 63, quad = lane >> 4, l15 = lane & 15;
  const unsigned short* Qb = QKg + (long)b * NN * 512;
  const unsigned short* Kb = Qb + 256;
  const unsigned short* Vb = Vtg + (long)b * CC * NN;

  // Q fragments (B-operand layout) for 2 q-blocks of 16 rows; row stride 512
  short8 qf[2][8];
#pragma unroll
  for (int qb = 0; qb < 2; qb++) {
    long qrow = q0 + wave * 32 + qb * 16 + l15;
#pragma unroll
    for (int ks = 0; ks < 8; ks++)
      qf[qb][ks] = *(const short8*)&Qb[qrow * 512 + ks * 32 + quad * 8];
  }

  floatx4 acc[2][16] = {};     // [qb][db] O d-blocks
  float rs[2] = {0.f, 0.f};    // per-lane partial row-sums (keys quad*4+r per tile)

  // bpermute lane indices for the in-register P transpose:
  // pf u0/u1 pull from src lane ((quad&1)*32 + l15); u2/u3 from +16 lanes.
  const int idx0 = (((lane >> 4) & 1) << 7) | ((lane & 15) << 2);
  const int idx1 = idx0 + 64;
  const bool lo32 = lane < 32;  // selects mt=0 data (quad<2) vs mt=1 (quad>=2)

  const int kbeg = sp * KSPLIT;

  // stage pair p (64 keys = 2 tiles) into ring half `buf`; 8 DMAs per wave
  auto stage_pair = [&](int p, int buf) {
#pragma unroll
    for (int tt = 0; tt < 2; tt++) {
      int m0 = kbeg + (p * 2 + tt) * 32;
      int slot = buf * 2 + tt;
#pragma unroll
      for (int st = 0; st < 2; st++) {
        int fg = st * 8 + wave;  // wave-uniform, 0..15
        dma16(&Kb[(long)(m0 + st * 16 + l15) * 512 + wave * 32 + quad * 8],
              &Kl[slot * 8192 + fg * 512]);
        dma16(&Vb[(long)(fg * 16 + l15) * NN + m0 + quad * 8],
              &Vl[slot * 8192 + fg * 512]);
      }
    }
  };

  __builtin_amdgcn_s_waitcnt(0xF70);  // drain Q loads so vmcnt tracks DMAs only
  stage_pair(0, 0);
  MEMFENCE;

  for (int p = 0; p < NPAIR; p++) {
    int buf = p & 1;
    S_BARRIER;  // all waves done reading ring half buf^1 -> overwrite ok
    MEMFENCE;
    if (p + 1 < NPAIR) {
      stage_pair(p + 1, buf ^ 1);
      MEMFENCE;
      __builtin_amdgcn_s_waitcnt(0xF78);  // vmcnt(8): pair-p DMAs done
    } else {
      __builtin_amdgcn_s_waitcnt(0xF70);  // vmcnt(0)
    }
    S_BARRIER;  // pair-p data visible to all waves
    MEMFENCE;

#pragma unroll
    for (int tt = 0; tt < 2; tt++) {
      int kb = (buf * 2 + tt) * 8192;
      // S^T = K Q^T : D[key][q], col=l15=q, row=quad*4+r=key (per 16-block mt)
      floatx4 s2[2][2];
      {
        floatx4 z = {0.f, 0.f, 0.f, 0.f};
        s2[0][0] = z; s2[0][1] = z; s2[1][0] = z; s2[1][1] = z;
      }
      __builtin_amdgcn_s_setprio(1);
#pragma unroll
      for (int fgk = 0; fgk < 16; fgk++) {
        short8 kf = *(const short8*)&Kl[kb + fgk * 512 + lane * 8];
        int mt = fgk >> 3, ks = fgk & 7;
        s2[0][mt] = MFMA(kf, qf[0][ks], s2[0][mt]);
        s2[1][mt] = MFMA(kf, qf[1][ks], s2[1][mt]);
      }
      __builtin_amdgcn_s_setprio(0);

      // p = 2^s (scale folded into Wq); pack key-pairs as bf16x2
      unsigned int pw[2][2][2];  // [qb][mt][h]: keys quad*4 + {2h,2h+1}
#pragma unroll
      for (int qb = 0; qb < 2; qb++)
#pragma unroll
        for (int mt = 0; mt < 2; mt++) {
          float e0 = __builtin_amdgcn_exp2f(s2[qb][mt][0]);
          float e1 = __builtin_amdgcn_exp2f(s2[qb][mt][1]);
          float e2 = __builtin_amdgcn_exp2f(s2[qb][mt][2]);
          float e3 = __builtin_amdgcn_exp2f(s2[qb][mt][3]);
          rs[qb] += (e0 + e1) + (e2 + e3);
          pw[qb][mt][0] = cvtpk_bf16(e0, e1);
          pw[qb][mt][1] = cvtpk_bf16(e2, e3);
        }

      // in-register transpose to PV A-frags: lane(quad=t,l15=q) needs keys
      // t*8+{0..7} of row q = pw[t>>1][h] from src quads 2(t&1), 2(t&1)+1
      short8 pf[2];
#pragma unroll
      for (int qb = 0; qb < 2; qb++) {
        unsigned int x0 = (unsigned int)__builtin_amdgcn_ds_bpermute(idx0, (int)pw[qb][0][0]);
        unsigned int y0 = (unsigned int)__builtin_amdgcn_ds_bpermute(idx0, (int)pw[qb][1][0]);
        unsigned int x1 = (unsigned int)__builtin_amdgcn_ds_bpermute(idx0, (int)pw[qb][0][1]);
        unsigned int y1 = (unsigned int)__builtin_amdgcn_ds_bpermute(idx0, (int)pw[qb][1][1]);
        unsigned int x2 = (unsigned int)__builtin_amdgcn_ds_bpermute(idx1, (int)pw[qb][0][0]);
        unsigned int y2 = (unsigned int)__builtin_amdgcn_ds_bpermute(idx1, (int)pw[qb][1][0]);
        unsigned int x3 = (unsigned int)__builtin_amdgcn_ds_bpermute(idx1, (int)pw[qb][0][1]);
        unsigned int y3 = (unsigned int)__builtin_amdgcn_ds_bpermute(idx1, (int)pw[qb][1][1]);
        union { unsigned int u[4]; short8 s; } pk;
        pk.u[0] = lo32 ? x0 : y0;
        pk.u[1] = lo32 ? x1 : y1;
        pk.u[2] = lo32 ? x2 : y2;
        pk.u[3] = lo32 ? x3 : y3;
        pf[qb] = pk.s;
      }

      __builtin_amdgcn_s_setprio(1);
#pragma unroll
      for (int db = 0; db < 16; db++) {
        short8 vf = *(const short8*)&Vl[kb + db * 512 + lane * 8];
        acc[0][db] = MFMA(pf[0], vf, acc[0][db]);
        acc[1][db] = MFMA(pf[1], vf, acc[1][db]);
      }
      __builtin_amdgcn_s_setprio(0);
    }
  }

  // epilogue: unnormalized partial O (scale 2^0) + per-row l
  unsigned short* Ob = Opart + (long)(b * NSPLIT + sp) * CC * NN;
#pragma unroll
  for (int qb = 0; qb < 2; qb++) {
    long nidx = q0 + wave * 32 + qb * 16 + quad * 4;
#pragma unroll
    for (int db = 0; db < 16; db++) {
      long d = db * 16 + l15;
      ushortx4 pk;
#pragma unroll
      for (int r = 0; r < 4; r++) pk[r] = f2bf(acc[qb][db][r]);
      *(ushortx4*)&Ob[d * NN + nidx] = pk;
    }
    // row-sum: rs holds keys {quad*4+r}; reduce across quads (lanes ^16, ^32)
    float v = rs[qb];
    v += __shfl_xor(v, 16, 64);
    v += __shfl_xor(v, 32, 64);
    if (quad == 0)
      Lp[(long)(b * NSPLIT + sp) * NN + q0 + wave * 32 + qb * 16 + l15] = v;
  }
}

// ---------------------------------------------------------------------------
// Phase 4: combine = sum partials, divide by total l. Block = 64 d x 64 n.
// ---------------------------------------------------------------------------
__global__ __launch_bounds__(256) void combine(const unsigned short* __restrict__ Op,
                                               const float* __restrict__ Lp,
                                               float* __restrict__ Out) {
  __shared__ float Wl[64];
  int b = blockIdx.z;
  int d0 = blockIdx.y * 64, n0 = blockIdx.x * 64;
  int t = threadIdx.x;
  if (t < 64) {
    int n = n0 + t;
    float L = 0.f;
#pragma unroll
    for (int s = 0; s < NSPLIT; s++) L += Lp[(long)(b * NSPLIT + s) * NN + n];
    Wl[t] = 1.0f / L;
  }
  __syncthreads();
  int tn = t & 15, td = t >> 4;
  int nb = n0 + tn * 4;
  float w[4];
#pragma unroll
  for (int r = 0; r < 4; r++) w[r] = Wl[tn * 4 + r];
#pragma unroll
  for (int dd = 0; dd < 4; dd++) {
    int d = d0 + td * 4 + dd;
    floatx4 o = {0.f, 0.f, 0.f, 0.f};
#pragma unroll
    for (int s = 0; s < NSPLIT; s++) {
      ushortx4 pv = *(const ushortx4*)&Op[((long)(b * NSPLIT + s) * CC + d) * NN + nb];
#pragma unroll
      for (int r = 0; r < 4; r++) o[r] += bf2f(pv[r]);
    }
#pragma unroll
    for (int r = 0; r < 4; r++) o[r] *= w[r];
    *(floatx4*)&Out[((long)b * CC + d) * NN + nb] = o;
  }
}

// ---------------------------------------------------------------------------
extern "C" void kernel_launch(void* const* d_in, const int* in_sizes, int n_in,
                              void* d_out, int out_size, void* d_ws, size_t ws_size,
                              hipStream_t stream) {
  const float* x = (const float*)d_in[0];
  const float* wq = (const float*)d_in[1];
  const float* wk = (const float*)d_in[2];
  const float* wv = (const float*)d_in[3];
  float* out = (float*)d_out;

  char* ws = (char*)d_ws;
  unsigned short* QKbuf = (unsigned short*)(ws);             // 16 MB (B,N,512)
  unsigned short* Vt = (unsigned short*)(ws + (16l << 20));  // 8 MB (B,C,N)
  // Xbf [24,32M) during prep+gemms; Opart [24,56M) written only by attn after
  // Xbf is dead -> safe overlap.
  unsigned short* Xbf = (unsigned short*)(ws + (24l << 20));   // 8 MB (B,N,C)
  unsigned short* Opart = (unsigned short*)(ws + (24l << 20)); // 32 MB (B,S,C,N)
  float* Lp = (float*)(ws + (56l << 20));                      // 256 KB
  unsigned short* Wqk = (unsigned short*)(ws + (57l << 20));   // 256 KB (512x256)
  unsigned short* Wv = (unsigned short*)(ws + (57l << 20) + (1 << 19));  // 128 KB
  float* PEt = (float*)(ws + (57l << 20) + (3 << 18));         // 64 KB (256x64)

  wcvt<<<dim3(CC * CC / 1024, 4), 256, 0, stream>>>(wq, wk, wv, Wqk, Wqk + CC * CC, Wv, PEt);
  prep_x<<<dim3(NN / 32, CC / 32, BB), dim3(32, 8), 0, stream>>>(x, PEt, Xbf);
  gemm_fused<<<dim3(768), 256, 0, stream>>>(Xbf, Wqk, Wv, QKbuf, Vt);
  attn<<<dim3(256), 512, 0, stream>>>(QKbuf, Vt, Opart, Lp);
  combine<<<dim3(NN / 64, CC / 64, BB), 256, 0, stream>>>(Opart, Lp, out);
}

// Round 12
// 189.631 us; speedup vs baseline: 1.0097x; 1.0097x over previous
//
#include <hip/hip_runtime.h>
#include <hip/hip_bf16.h>

#define BB 4
#define CC 256
#define NN 4096
#define NSPLIT 4
#define KSPLIT (NN / NSPLIT)
#define NT (KSPLIT / 32)

typedef __attribute__((ext_vector_type(8))) short short8;
typedef __attribute__((ext_vector_type(4))) float floatx4;
typedef __attribute__((ext_vector_type(4))) unsigned short ushortx4;

__device__ __forceinline__ float bf2f(unsigned short u) {
  union { unsigned int i; float f; } cv; cv.i = ((unsigned int)u) << 16; return cv.f;
}
__device__ __forceinline__ unsigned short f2bf(float f) {
  union { __hip_bfloat16 h; unsigned short u; } cv; cv.h = __float2bfloat16(f); return cv.u;
}
// pack two f32 -> two bf16 in one u32 (src0 -> low16). No builtin on gfx950.
__device__ __forceinline__ unsigned int cvtpk_bf16(float lo, float hi) {
  unsigned int r;
  asm("v_cvt_pk_bf16_f32 %0, %1, %2" : "=v"(r) : "v"(lo), "v"(hi));
  return r;
}

#define MFMA(a, b, c) __builtin_amdgcn_mfma_f32_16x16x32_bf16((a), (b), (c), 0, 0, 0)

// async global->LDS DMA, 16B/lane, LDS dest = wave-uniform base + lane*16
__device__ __forceinline__ void dma16(const unsigned short* g, unsigned short* l) {
  __builtin_amdgcn_global_load_lds(
      (const __attribute__((address_space(1))) unsigned int*)g,
      (__attribute__((address_space(3))) unsigned int*)l, 16, 0, 0);
}
#define S_BARRIER __builtin_amdgcn_s_barrier()
#define MEMFENCE __asm__ volatile("" ::: "memory")
#define SCHED_FENCE __builtin_amdgcn_sched_barrier(0)

// ---------------------------------------------------------------------------
// Phase 0: fp32 weights -> bf16 (y<3). Wq pre-scaled by C^-0.5 * log2(e).
// y==3: build the 256x64 positional-encoding table PEt[c][pos].
// PEt[c][p] = (c&64) ? cos(p * f) : sin(p * f),  f = 10000^-((c&63)/64).
// ---------------------------------------------------------------------------
__global__ __launch_bounds__(256) void wcvt(const float* __restrict__ w0,
                                            const float* __restrict__ w1,
                                            const float* __restrict__ w2,
                                            unsigned short* __restrict__ o0,
                                            unsigned short* __restrict__ o1,
                                            unsigned short* __restrict__ o2,
                                            float* __restrict__ PEt) {
  if (blockIdx.y == 3) {  // PE table: 64 blocks x 256 thr = 16384 entries
    int idx = blockIdx.x * 256 + threadIdx.x;
    int c = idx >> 6, p = idx & 63, j = c & 63;
    float freq = exp2f(-0.2076205059304601f * (float)j);  // 10000^(-j/64)
    float arg = (float)p * freq;
    PEt[idx] = (c & 64) ? cosf(arg) : sinf(arg);
    return;
  }
  const float* w = (blockIdx.y == 0) ? w0 : (blockIdx.y == 1) ? w1 : w2;
  unsigned short* o = (blockIdx.y == 0) ? o0 : (blockIdx.y == 1) ? o1 : o2;
  float s = (blockIdx.y == 0) ? 0.0901684400555590f : 1.0f;  // 0.0625*log2(e)
  int i = (blockIdx.x * 256 + threadIdx.x) * 4;
  floatx4 v = *(const floatx4*)&w[i];
  ushortx4 p;
#pragma unroll
  for (int r = 0; r < 4; r++) p[r] = f2bf(v[r] * s);
  *(ushortx4*)&o[i] = p;
}

// ---------------------------------------------------------------------------
// Phase 1: Xbf[b][n][c] = bf16( x[b][c][n] + PEt[c][w or h] ), LDS transpose.
// ---------------------------------------------------------------------------
__global__ __launch_bounds__(256) void prep_x(const float* __restrict__ x,
                                              const float* __restrict__ PEt,
                                              unsigned short* __restrict__ Xbf) {
  __shared__ float tile[32][33];
  int b = blockIdx.z;
  int n0 = blockIdx.x * 32, c0 = blockIdx.y * 32;
  int tx = threadIdx.x, ty = threadIdx.y;
#pragma unroll
  for (int i = 0; i < 4; i++) {
    int c = c0 + ty + i * 8;
    int n = n0 + tx;
    float v = x[((long)(b * CC + c)) * NN + n];
    int hh = n >> 6, ww = n & 63;
    v += PEt[(c << 6) | ((c < 128) ? ww : hh)];
    tile[ty + i * 8][tx] = v;
  }
  __syncthreads();
#pragma unroll
  for (int i = 0; i < 4; i++) {
    int n = n0 + ty + i * 8;
    int c = c0 + tx;
    Xbf[((long)(b * NN + n)) * CC + c] = f2bf(tile[tx][ty + i * 8]);
  }
}

// ---------------------------------------------------------------------------
// Phase 2 (m97-class): fused 128x128-tile GEMM, C = A * Bt^T, K=256, bf16.
// Flat grid 768: F<512 -> QK = Xbf * Wqk^T (4096x512/batch);
//                F>=512 -> Vt = Wv * Xbf^T (256x4096/batch).
// ---------------------------------------------------------------------------
__global__ __launch_bounds__(256, 2) void gemm_fused(const unsigned short* __restrict__ Xbf,
                                                     const unsigned short* __restrict__ Wqk,
                                                     const unsigned short* __restrict__ Wv,
                                                     unsigned short* __restrict__ QK,
                                                     unsigned short* __restrict__ Vt) {
  __shared__ alignas(16) unsigned short Af[2][8 * 512];  // 8 KB per buf
  __shared__ alignas(16) unsigned short Bf[2][8 * 512];
  const unsigned short *Ab, *Bb;
  unsigned short* Ob;
  long row0, col0;
  int ldo;
  int F = blockIdx.x;
  if (F < 512) {  // QK projection: A=Xbf(4096x256), Bt=Wqk(512x256), O=(B,N,512)
    int b = F >> 7, r = F & 127;
    row0 = (long)(r >> 2) * 128;  // 32 row tiles
    col0 = (long)(r & 3) * 128;   // 4 col tiles
    Ab = Xbf + (long)b * NN * CC;
    Bb = Wqk;
    Ob = QK + (long)b * NN * 512;
    ldo = 512;
  } else {  // Vt: A=Wv(256x256), Bt=Xbf(4096x256), O=(B,C,N)
    int F2 = F - 512;
    int b = F2 >> 6, r = F2 & 63;
    row0 = (long)(r >> 5) * 128;  // 2 row tiles
    col0 = (long)(r & 31) * 128;  // 32 col tiles
    Ab = Wv;
    Bb = Xbf + (long)b * NN * CC;
    Ob = Vt + (long)b * CC * NN;
    ldo = NN;
  }
  int t = threadIdx.x, wave = t >> 6, lane = t & 63, quad = lane >> 4, l15 = lane & 15;
  int wr = wave >> 1, wc = wave & 1;

  // stage k-chunk [k0,k0+32) into buffer `buf`: 16 fragment-groups, 4/wave
  auto stage = [&](int k0, int buf) {
#pragma unroll
    for (int i = 0; i < 2; i++) {
      int fg = wave * 2 + i;  // 0..7, wave-uniform
      dma16(&Ab[(row0 + fg * 16 + l15) * 256 + k0 + quad * 8], &Af[buf][fg * 512]);
      dma16(&Bb[(col0 + fg * 16 + l15) * 256 + k0 + quad * 8], &Bf[buf][fg * 512]);
    }
  };

  floatx4 acc[4][4] = {};
  stage(0, 0);
  MEMFENCE;
#pragma unroll
  for (int ki = 0; ki < 8; ki++) {
    int buf = ki & 1;
    S_BARRIER;  // all waves done reading buf (from step ki-2) -> overwrite ok
    MEMFENCE;
    if (ki + 1 < 8) {
      stage((ki + 1) * 32, buf ^ 1);
      MEMFENCE;
      __builtin_amdgcn_s_waitcnt(0xF74);  // vmcnt(4): my step-ki DMAs done
    } else {
      __builtin_amdgcn_s_waitcnt(0xF70);  // vmcnt(0)
    }
    S_BARRIER;  // step-ki fragments visible to all waves
    MEMFENCE;
    short8 af[4], bf[4];
#pragma unroll
    for (int i = 0; i < 4; i++) {
      af[i] = *(const short8*)&Af[buf][(wr * 4 + i) * 512 + lane * 8];
      bf[i] = *(const short8*)&Bf[buf][(wc * 4 + i) * 512 + lane * 8];
    }
#pragma unroll
    for (int i = 0; i < 4; i++)
#pragma unroll
      for (int j = 0; j < 4; j++) acc[i][j] = MFMA(af[i], bf[j], acc[i][j]);
  }

  // C/D layout (m89): col = l15, row = quad*4 + r (within each 16x16 block)
#pragma unroll
  for (int i = 0; i < 4; i++)
#pragma unroll
    for (int j = 0; j < 4; j++) {
      long col = col0 + (wc * 4 + j) * 16 + l15;
#pragma unroll
      for (int r = 0; r < 4; r++) {
        long row = row0 + (wr * 4 + i) * 16 + quad * 4 + r;
        Ob[row * (long)ldo + col] = f2bf(acc[i][j][r]);
      }
    }
}

// ---------------------------------------------------------------------------
// Phase 3: flash attention, no online max (|s*sc| <= ~35 log2-units, safe).
// Round-12: TWO INDEPENDENT BARRIER DOMAINS per CU. 4-wave WG (256 thr) =
// 128 q-rows; each wave keeps qb=2 x 16 = 32 q-rows (round-4's regression
// was qb=1 -- avoided). Grid 512 = 2 WGs/CU: LDS halved to 64 KB via a
// tile-granularity 2-slot ring; __launch_bounds__(256,2) caps regs at 256
// so 2x4 waves fit the 512-reg/SIMD pool. WG0's softmax/barrier phases
// overlap WG1's MFMA phases (r1 counters: MfmaUtil 27% vs 33us MFMA floor).
// Schedule = round-4's VERIFIED tile-granularity discipline:
//   B1 -> stage(t+1) -> vmcnt(8) -> B2 -> compute(t).
// Ledger: prologue 8 DMAs out; region issues +8 -> vmcnt(8) completes
// exactly tile t; tail vmcnt(0); slot (t+1)&1 last read before this B1.
// HAZARD HARDENING (round-10 lesson): sched_barrier(0) after every manual
// waitcnt and after B2 -- hipcc's machine scheduler hoisted Kl/Vl ds_reads
// above manual vmcnt waits when codegen shifted (setprio was the accidental
// fence). setprio brackets retained (also load-bearing).
// Staging reindex for 4 waves: fg = st*8 + (wave*2+i); K d-offset
// (wave*2+i)*32 = (fg&7)*32 matches consumer ks=fgk&7. V: fg = db.
// SWAPPED QK^T (T12): S = MFMA(K,Q) puts q on l15; in-register P transpose
// via exp2 -> cvt_pk -> ds_bpermute + cndmask (verified r1).
// QK layout (B,N,512): [0:256)=Q (pre-scaled), [256:512)=K. Vt (B,C,N).
// Grid map: c = F>>5 (b,sp), qt = F&31 -> XCD-mates share one c's K/V in L2.
// ---------------------------------------------------------------------------
__global__ __launch_bounds__(256, 2) void attn(const unsigned short* __restrict__ QKg,
                                               const unsigned short* __restrict__ Vtg,
                                               unsigned short* __restrict__ Opart,
                                               float* __restrict__ Lp) {
  __shared__ alignas(16) unsigned short Kl[2 * 8192];   // 2 slots x (32 keys x 256 d)
  __shared__ alignas(16) unsigned short Vl[2 * 8192];   // 2 slots x (256 d x 32 keys)
  int F = blockIdx.x;
  int c = F >> 5, qt = F & 31;
  int sp = c & 3, b = c >> 2;
  long q0 = (long)qt * 128;
  int t = threadIdx.x, wave = t >> 6, lane = t & 63, quad = lane >> 4, l15 = lane & 15;
  const unsigned short* Qb = QKg + (long)b * NN * 512;
  const unsigned short* Kb = Qb + 256;
  const unsigned short* Vb = Vtg + (long)b * CC * NN;

  // Q fragments (B-operand layout) for 2 q-blocks of 16 rows; row stride 512
  short8 qf[2][8];
#pragma unroll
  for (int qb = 0; qb < 2; qb++) {
    long qrow = q0 + wave * 32 + qb * 16 + l15;
#pragma unroll
    for (int ks = 0; ks < 8; ks++)
      qf[qb][ks] = *(const short8*)&Qb[qrow * 512 + ks * 32 + quad * 8];
  }

  floatx4 acc[2][16] = {};     // [qb][db] O d-blocks
  float rs[2] = {0.f, 0.f};    // per-lane partial row-sums (keys quad*4+r per tile)

  // bpermute lane indices for the in-register P transpose (verified r1):
  const int idx0 = (((lane >> 4) & 1) << 7) | ((lane & 15) << 2);
  const int idx1 = idx0 + 64;
  const bool lo32 = lane < 32;  // selects mt=0 data (quad<2) vs mt=1 (quad>=2)

  const int kbeg = sp * KSPLIT;

  // stage tile tt (32 keys) into ring slot tt&1; 8 DMAs per wave (4 K + 4 V)
  auto stageT = [&](int tt) {
    int m0 = kbeg + tt * 32;
    int kb = (tt & 1) * 8192;
#pragma unroll
    for (int st = 0; st < 2; st++) {
#pragma unroll
      for (int i = 0; i < 2; i++) {
        int d = wave * 2 + i;        // 0..7, wave-uniform
        int fg = st * 8 + d;         // bijective onto 0..15
        dma16(&Kb[(long)(m0 + st * 16 + l15) * 512 + d * 32 + quad * 8],
              &Kl[kb + fg * 512]);
        dma16(&Vb[(long)(fg * 16 + l15) * NN + m0 + quad * 8],
              &Vl[kb + fg * 512]);
      }
    }
  };

  // --- prologue: drain qf loads so vmcnt tracks DMAs only, then stage(0) ---
  MEMFENCE;
  __builtin_amdgcn_s_waitcnt(0x070);  // vmcnt(0) lgkmcnt(0)
  SCHED_FENCE;
  MEMFENCE;
  stageT(0);
  MEMFENCE;

#pragma unroll 1
  for (int tt = 0; tt < NT; tt++) {
    S_BARRIER;  // B1: all reads of slot (tt+1)&1 (tile tt-1) are done
    MEMFENCE;
    SCHED_FENCE;
    if (tt + 1 < NT) {
      stageT(tt + 1);
      MEMFENCE;
      __builtin_amdgcn_s_waitcnt(0xF78);  // vmcnt(8): tile tt's DMAs done
    } else {
      __builtin_amdgcn_s_waitcnt(0xF70);  // vmcnt(0): last tile done
    }
    SCHED_FENCE;  // nothing (esp. ds_reads) may hoist above the wait
    S_BARRIER;    // B2: tile tt visible to all waves
    MEMFENCE;
    SCHED_FENCE;

    int kb = (tt & 1) * 8192;

    // S^T = K Q^T : D[key][q], col=l15=q, row=quad*4+r=key (per 16-block mt)
    floatx4 s2[2][2];
    {
      floatx4 z = {0.f, 0.f, 0.f, 0.f};
      s2[0][0] = z; s2[0][1] = z; s2[1][0] = z; s2[1][1] = z;
    }
    __builtin_amdgcn_s_setprio(1);
#pragma unroll
    for (int fgk = 0; fgk < 16; fgk++) {
      short8 kf = *(const short8*)&Kl[kb + fgk * 512 + lane * 8];
      int mt = fgk >> 3, ks = fgk & 7;
      s2[0][mt] = MFMA(kf, qf[0][ks], s2[0][mt]);
      s2[1][mt] = MFMA(kf, qf[1][ks], s2[1][mt]);
    }
    __builtin_amdgcn_s_setprio(0);

    // p = 2^s (scale folded into Wq); pack key-pairs as bf16x2
    unsigned int pw[2][2][2];  // [qb][mt][h]: keys quad*4 + {2h,2h+1}
#pragma unroll
    for (int qb = 0; qb < 2; qb++)
#pragma unroll
      for (int mt = 0; mt < 2; mt++) {
        float e0 = __builtin_amdgcn_exp2f(s2[qb][mt][0]);
        float e1 = __builtin_amdgcn_exp2f(s2[qb][mt][1]);
        float e2 = __builtin_amdgcn_exp2f(s2[qb][mt][2]);
        float e3 = __builtin_amdgcn_exp2f(s2[qb][mt][3]);
        rs[qb] += (e0 + e1) + (e2 + e3);
        pw[qb][mt][0] = cvtpk_bf16(e0, e1);
        pw[qb][mt][1] = cvtpk_bf16(e2, e3);
      }

    // in-register transpose to PV A-frags: lane(quad=t,l15=q) needs keys
    // t*8+{0..7} of row q = pw[t>>1][h] from src quads 2(t&1), 2(t&1)+1
    short8 pf[2];
#pragma unroll
    for (int qb = 0; qb < 2; qb++) {
      unsigned int x0 = (unsigned int)__builtin_amdgcn_ds_bpermute(idx0, (int)pw[qb][0][0]);
      unsigned int y0 = (unsigned int)__builtin_amdgcn_ds_bpermute(idx0, (int)pw[qb][1][0]);
      unsigned int x1 = (unsigned int)__builtin_amdgcn_ds_bpermute(idx0, (int)pw[qb][0][1]);
      unsigned int y1 = (unsigned int)__builtin_amdgcn_ds_bpermute(idx0, (int)pw[qb][1][1]);
      unsigned int x2 = (unsigned int)__builtin_amdgcn_ds_bpermute(idx1, (int)pw[qb][0][0]);
      unsigned int y2 = (unsigned int)__builtin_amdgcn_ds_bpermute(idx1, (int)pw[qb][1][0]);
      unsigned int x3 = (unsigned int)__builtin_amdgcn_ds_bpermute(idx1, (int)pw[qb][0][1]);
      unsigned int y3 = (unsigned int)__builtin_amdgcn_ds_bpermute(idx1, (int)pw[qb][1][1]);
      union { unsigned int u[4]; short8 s; } pk;
      pk.u[0] = lo32 ? x0 : y0;
      pk.u[1] = lo32 ? x1 : y1;
      pk.u[2] = lo32 ? x2 : y2;
      pk.u[3] = lo32 ? x3 : y3;
      pf[qb] = pk.s;
    }

    __builtin_amdgcn_s_setprio(1);
#pragma unroll
    for (int db = 0; db < 16; db++) {
      short8 vf = *(const short8*)&Vl[kb + db * 512 + lane * 8];
      acc[0][db] = MFMA(pf[0], vf, acc[0][db]);
      acc[1][db] = MFMA(pf[1], vf, acc[1][db]);
    }
    __builtin_amdgcn_s_setprio(0);
  }

  // epilogue: unnormalized partial O (scale 2^0) + per-row l
  unsigned short* Ob = Opart + (long)(b * NSPLIT + sp) * CC * NN;
#pragma unroll
  for (int qb = 0; qb < 2; qb++) {
    long nidx = q0 + wave * 32 + qb * 16 + quad * 4;
#pragma unroll
    for (int db = 0; db < 16; db++) {
      long d = db * 16 + l15;
      ushortx4 pk;
#pragma unroll
      for (int r = 0; r < 4; r++) pk[r] = f2bf(acc[qb][db][r]);
      *(ushortx4*)&Ob[d * NN + nidx] = pk;
    }
    // row-sum: rs holds keys {quad*4+r}; reduce across quads (lanes ^16, ^32)
    float v = rs[qb];
    v += __shfl_xor(v, 16, 64);
    v += __shfl_xor(v, 32, 64);
    if (quad == 0)
      Lp[(long)(b * NSPLIT + sp) * NN + q0 + wave * 32 + qb * 16 + l15] = v;
  }
}

// ---------------------------------------------------------------------------
// Phase 4: combine = sum partials, divide by total l. Block = 64 d x 64 n.
// ---------------------------------------------------------------------------
__global__ __launch_bounds__(256) void combine(const unsigned short* __restrict__ Op,
                                               const float* __restrict__ Lp,
                                               float* __restrict__ Out) {
  __shared__ float Wl[64];
  int b = blockIdx.z;
  int d0 = blockIdx.y * 64, n0 = blockIdx.x * 64;
  int t = threadIdx.x;
  if (t < 64) {
    int n = n0 + t;
    float L = 0.f;
#pragma unroll
    for (int s = 0; s < NSPLIT; s++) L += Lp[(long)(b * NSPLIT + s) * NN + n];
    Wl[t] = 1.0f / L;
  }
  __syncthreads();
  int tn = t & 15, td = t >> 4;
  int nb = n0 + tn * 4;
  float w[4];
#pragma unroll
  for (int r = 0; r < 4; r++) w[r] = Wl[tn * 4 + r];
#pragma unroll
  for (int dd = 0; dd < 4; dd++) {
    int d = d0 + td * 4 + dd;
    floatx4 o = {0.f, 0.f, 0.f, 0.f};
#pragma unroll
    for (int s = 0; s < NSPLIT; s++) {
      ushortx4 pv = *(const ushortx4*)&Op[((long)(b * NSPLIT + s) * CC + d) * NN + nb];
#pragma unroll
      for (int r = 0; r < 4; r++) o[r] += bf2f(pv[r]);
    }
#pragma unroll
    for (int r = 0; r < 4; r++) o[r] *= w[r];
    *(floatx4*)&Out[((long)b * CC + d) * NN + nb] = o;
  }
}

// ---------------------------------------------------------------------------
extern "C" void kernel_launch(void* const* d_in, const int* in_sizes, int n_in,
                              void* d_out, int out_size, void* d_ws, size_t ws_size,
                              hipStream_t stream) {
  const float* x = (const float*)d_in[0];
  const float* wq = (const float*)d_in[1];
  const float* wk = (const float*)d_in[2];
  const float* wv = (const float*)d_in[3];
  float* out = (float*)d_out;

  char* ws = (char*)d_ws;
  unsigned short* QKbuf = (unsigned short*)(ws);             // 16 MB (B,N,512)
  unsigned short* Vt = (unsigned short*)(ws + (16l << 20));  // 8 MB (B,C,N)
  // Xbf [24,32M) during prep+gemms; Opart [24,56M) written only by attn after
  // Xbf is dead -> safe overlap.
  unsigned short* Xbf = (unsigned short*)(ws + (24l << 20));   // 8 MB (B,N,C)
  unsigned short* Opart = (unsigned short*)(ws + (24l << 20)); // 32 MB (B,S,C,N)
  float* Lp = (float*)(ws + (56l << 20));                      // 256 KB
  unsigned short* Wqk = (unsigned short*)(ws + (57l << 20));   // 256 KB (512x256)
  unsigned short* Wv = (unsigned short*)(ws + (57l << 20) + (1 << 19));  // 128 KB
  float* PEt = (float*)(ws + (57l << 20) + (3 << 18));         // 64 KB (256x64)

  wcvt<<<dim3(CC * CC / 1024, 4), 256, 0, stream>>>(wq, wk, wv, Wqk, Wqk + CC * CC, Wv, PEt);
  prep_x<<<dim3(NN / 32, CC / 32, BB), dim3(32, 8), 0, stream>>>(x, PEt, Xbf);
  gemm_fused<<<dim3(768), 256, 0, stream>>>(Xbf, Wqk, Wv, QKbuf, Vt);
  attn<<<dim3(512), 256, 0, stream>>>(QKbuf, Vt, Opart, Lp);
  combine<<<dim3(NN / 64, CC / 64, BB), 256, 0, stream>>>(Opart, Lp, out);
}